// Round 7
// baseline (893.812 us; speedup 1.0000x reference)
//
#include <hip/hip_runtime.h>
#include <math.h>

#define LOD 64
#define LSD 128
#define KK 16
#define BB 128
#define TT 96
#define OBSD 128
#define ENC 512
#define CH 128
#define OUTD 64
#define TMP 132   // tm2 row pad
#define W1P 129   // w1T row pad (odd -> 2-way bank alias max, free)

__device__ __forceinline__ float elup1f(float x) {
    return x >= 0.0f ? x + 1.0f : expf(x);
}

// ---------------- clock probe: 150000 dependent FMAs ~= 600K cycles ----------------
// dur_us of this dispatch => effective clock = 600e3 / dur_us (MHz-ish check).
// Writes into the basis workspace region, which prep_basis overwrites afterwards.
__global__ __launch_bounds__(256, 1)
void clock_probe(float* __restrict__ out) {
    float x = (float)threadIdx.x * 1e-9f + 1.0f;
    #pragma clang loop unroll_count(16)
    for (int i = 0; i < 150000; ++i)
        x = __builtin_fmaf(x, 0.9999999f, 1e-9f);
    out[threadIdx.x] = x;   // racy across blocks; region overwritten by prep_basis
}

// ---------------- prep: band-compress basis (entry e = 14*row + s) ----------------
__global__ void prep_basis(const float* __restrict__ tm11, const float* __restrict__ tm12,
                           const float* __restrict__ tm21, const float* __restrict__ tm22,
                           float* __restrict__ basis) {
    int e = blockIdx.x * blockDim.x + threadIdx.x;
    if (e >= 16 * 128 * 14) return;
    int k = e / (128 * 14);
    int rem = e % (128 * 14);
    int row = rem / 14;
    int s = rem % 14;
    int r = row & 63;
    int half = row >> 6;
    int sub = (s >= 7) ? 1 : 0;
    int ss = s - sub * 7;
    int col = r - 3 + ss;
    float v = 0.0f;
    if (col >= 0 && col < 64) {
        const float* src = half ? (sub ? tm22 : tm21) : (sub ? tm12 : tm11);
        v = src[k * 4096 + r * 64 + col];
    }
    basis[e] = v;
}

// ---------------- encoder (unchanged) ----------------
#define EROWS 16
__global__ __launch_bounds__(256, 2)
void encoder_kernel(const float* __restrict__ obs,
                    const float* __restrict__ enc_W, const float* __restrict__ enc_b,
                    const float* __restrict__ wmean_W, const float* __restrict__ wmean_b,
                    const float* __restrict__ wcov_W, const float* __restrict__ wcov_b,
                    float* __restrict__ wm_out, float* __restrict__ wc_out) {
    __shared__ float obs_s[EROWS][OBSD];
    __shared__ float h_s[EROWS][ENC];
    __shared__ float wm_s[EROWS][LOD];
    __shared__ float norm_s[EROWS];
    int tid = threadIdx.x;
    long row0 = (long)blockIdx.x * EROWS;

    for (int idx = tid; idx < EROWS * OBSD; idx += 256) {
        int r = idx >> 7, c = idx & 127;
        obs_s[r][c] = obs[(row0 + r) * OBSD + c];
    }
    __syncthreads();

    for (int p = 0; p < 2; ++p) {
        int c = tid + p * 256;
        float acc[EROWS];
        #pragma unroll
        for (int r = 0; r < EROWS; ++r) acc[r] = 0.f;
        for (int j = 0; j < OBSD; ++j) {
            float w = enc_W[j * ENC + c];
            #pragma unroll
            for (int r = 0; r < EROWS; ++r) acc[r] += obs_s[r][j] * w;
        }
        float b = enc_b[c];
        #pragma unroll
        for (int r = 0; r < EROWS; ++r) h_s[r][c] = fmaxf(acc[r] + b, 0.f);
    }
    __syncthreads();

    {
        int c = tid & 63, g = tid >> 6;
        const float* W = (g < 2) ? wmean_W : wcov_W;
        int r0 = (g & 1) * 8;
        float acc[8];
        #pragma unroll
        for (int r = 0; r < 8; ++r) acc[r] = 0.f;
        for (int j = 0; j < ENC; ++j) {
            float w = W[j * LOD + c];
            #pragma unroll
            for (int r = 0; r < 8; ++r) acc[r] += h_s[r0 + r][j] * w;
        }
        if (g < 2) {
            float b = wmean_b[c];
            #pragma unroll
            for (int r = 0; r < 8; ++r) wm_s[r0 + r][c] = acc[r] + b;
        } else {
            float b = wcov_b[c];
            #pragma unroll
            for (int r = 0; r < 8; ++r)
                wc_out[(row0 + r0 + r) * LOD + c] = elup1f(acc[r] + b);
        }
    }
    __syncthreads();
    if (tid < EROWS) {
        float ss = 0.f;
        for (int c = 0; c < 64; ++c) { float v = wm_s[tid][c]; ss += v * v; }
        norm_s[tid] = sqrtf(ss);
    }
    __syncthreads();
    for (int idx = tid; idx < EROWS * LOD; idx += 256) {
        int r = idx >> 6, c = idx & 63;
        wm_out[(row0 + r) * LOD + c] = wm_s[r][c] / norm_s[r];
    }
}

// ---------------- scan: 2 waves (128 thr), 5 barriers, lane owns a full hh column ----------------
// P1 (all): hh[c] = relu(dot(meanQ, w1T[c]) + b1) — full column from LDS-staged cW1^T.
// L  (all): logit partials, 16-col chunks, xor16/32 reduce -> part_s[16][2].
// S  (w0) : in-lane softmax over 16 logits (no shuffles), lanes 0-3 write ck.
// T  (all): lane owns band row tid (14 entries x Sigma_16) from register basis.
// FG (w0) : carries in registers (shfl taps), mean window prefetched; Kalman; post->LDS.
__global__ __launch_bounds__(128, 1)
void scan_kernel(const float* __restrict__ wm_g, const float* __restrict__ wc_g,
                 const float* __restrict__ cW1, const float* __restrict__ cb1,
                 const float* __restrict__ cW2, const float* __restrict__ cb2,
                 const float* __restrict__ basis, const float* __restrict__ log_tc,
                 float* __restrict__ post_g) {
    extern __shared__ __align__(16) float smem[];   // post_l: 12288 floats
    float* post_l = smem;

    __shared__ __align__(16) float w1T[128 * W1P];     // cW1 transposed, padded
    __shared__ __align__(16) float meanQ_raw[136];     // [4 pad | 128 | 4 pad]
    __shared__ __align__(16) float hh_s[LSD];
    __shared__ __align__(16) float part_s[32];         // [k][wave]
    __shared__ __align__(16) float ck_s[16];
    __shared__ float tm2[16 * TMP];                    // [slot s][row r]

    float* meanQ = meanQ_raw + 4;

    int tid = threadIdx.x;   // 0..127
    int b = blockIdx.x;
    int w = tid >> 6;        // wave 0/1
    int l = tid & 63;        // lane

    // --- stage cW1 transposed into LDS (one-time) ---
    for (int jj = 0; jj < 128; ++jj)
        w1T[tid * W1P + jj] = cW1[jj * 128 + tid];

    // --- persistent registers ---
    float br[16][14];        // basis entries e = 14*tid + j, all 16 k
    #pragma unroll
    for (int q = 0; q < 16; ++q)
        #pragma unroll
        for (int j = 0; j < 14; ++j)
            br[q][j] = basis[q * 1792 + 14 * tid + j];

    float cb1r = cb1[tid];

    int k = tid & 15;
    int p = tid >> 4;        // 0..7 (16-col chunk)
    float w2r[16];           // cW2[(16p+u)][k]
    #pragma unroll
    for (int u = 0; u < 16; ++u)
        w2r[u] = cW2[(16 * p + u) * 16 + k];
    float cb2r = cb2[k];

    // FG state (wave 0): carries in registers, lane l owns row l
    float cuR = 10.f, clR = 10.f, csR = 0.f;
    float tcu_r = elup1f(log_tc[l]);
    float tcl_r = elup1f(log_tc[64 + l]);

    long wmbase = (long)b * (TT * 64);

    // --- init shared mean (+pads) ---
    for (int idx = tid; idx < 136; idx += 128) meanQ_raw[idx] = 0.f;
    __syncthreads();

    #pragma clang loop unroll(disable)
    for (int t = 0; t < TT; ++t) {
        // wave-0 prefetch: wm/wc from global (L2), mean windows from LDS.
        float wmv = 0.f, wcv = 0.f;
        float muw[7], mlw[7];
        if (w == 0) {
            wmv = wm_g[wmbase + t * 64 + l];
            wcv = wc_g[wmbase + t * 64 + l];
            #pragma unroll
            for (int d = 0; d < 7; ++d) {
                muw[d] = meanQ[l + d - 3];
                mlw[d] = meanQ[64 + l + d - 3];
            }
        }

        // ---- P1: full-column hh dot ----
        {
            const float* wrow = w1T + tid * W1P;
            const float4* mq = (const float4*)meanQ;
            float a0 = 0.f, a1 = 0.f, a2 = 0.f, a3 = 0.f;
            #pragma unroll
            for (int j4 = 0; j4 < 32; ++j4) {
                float4 m4 = mq[j4];
                a0 += m4.x * wrow[4 * j4 + 0];
                a1 += m4.y * wrow[4 * j4 + 1];
                a2 += m4.z * wrow[4 * j4 + 2];
                a3 += m4.w * wrow[4 * j4 + 3];
            }
            hh_s[tid] = fmaxf(a0 + a1 + a2 + a3 + cb1r, 0.f);
        }
        __syncthreads();   // BAR 1

        // ---- L: logit partials over 16-col chunk p ----
        {
            const float4* hq = (const float4*)(hh_s + 16 * p);
            float4 h0 = hq[0], h1 = hq[1], h2 = hq[2], h3 = hq[3];
            float pl = h0.x * w2r[0]  + h0.y * w2r[1]  + h0.z * w2r[2]  + h0.w * w2r[3]
                     + h1.x * w2r[4]  + h1.y * w2r[5]  + h1.z * w2r[6]  + h1.w * w2r[7]
                     + h2.x * w2r[8]  + h2.y * w2r[9]  + h2.z * w2r[10] + h2.w * w2r[11]
                     + h3.x * w2r[12] + h3.y * w2r[13] + h3.z * w2r[14] + h3.w * w2r[15];
            pl += __shfl_xor(pl, 16, 64);
            pl += __shfl_xor(pl, 32, 64);
            if (l < 16) part_s[2 * k + w] = pl + ((w == 0) ? cb2r : 0.f);
        }
        __syncthreads();   // BAR 2

        // ---- S (wave 0): in-lane softmax over 16 logits ----
        if (w == 0) {
            const float4* pq = (const float4*)part_s;   // 8 quads
            float e[16];
            float sm = 0.f;
            #pragma unroll
            for (int i = 0; i < 8; ++i) {
                float4 q = pq[i];
                float ea = __expf(q.x + q.y);
                float eb = __expf(q.z + q.w);
                e[2 * i] = ea; e[2 * i + 1] = eb;
                sm += ea + eb;
            }
            float inv = 1.f / sm;
            if (l < 4) {
                float4 v;
                v.x = e[4 * l + 0] * inv;
                v.y = e[4 * l + 1] * inv;
                v.z = e[4 * l + 2] * inv;
                v.w = e[4 * l + 3] * inv;
                ((float4*)ck_s)[l] = v;
            }
        }
        __syncthreads();   // BAR 3

        // ---- T: band row tid, 14 entries ----
        {
            float4 c0 = *(const float4*)(ck_s + 0);
            float4 c1 = *(const float4*)(ck_s + 4);
            float4 c2 = *(const float4*)(ck_s + 8);
            float4 c3 = *(const float4*)(ck_s + 12);
            float ck[16] = {c0.x, c0.y, c0.z, c0.w, c1.x, c1.y, c1.z, c1.w,
                            c2.x, c2.y, c2.z, c2.w, c3.x, c3.y, c3.z, c3.w};
            #pragma unroll
            for (int j = 0; j < 14; ++j) {
                float acc = 0.f;
                #pragma unroll
                for (int q = 0; q < 16; ++q) acc += ck[q] * br[q][j];
                tm2[j * TMP + tid] = acc;
            }
        }
        __syncthreads();   // BAR 4

        // ---- FG (wave 0): banded propagation + Kalman ----
        if (w == 0) {
            int i = l;
            float cun[7], csn[7], cln[7];
            #pragma unroll
            for (int d = 0; d < 7; ++d) {
                int src = i + d - 3;
                cun[d] = __shfl(cuR, src, 64);
                csn[d] = __shfl(csR, src, 64);
                cln[d] = __shfl(clR, src, 64);
            }
            float ncu = tcu_r, ncl = tcl_r, ncs = 0.f, au = 0.f, al = 0.f;
            #pragma unroll
            for (int s = 0; s < 7; ++s) {
                float A  = tm2[s * TMP + i];
                float Bv = tm2[(7 + s) * TMP + i];
                float C  = tm2[s * TMP + 64 + i];
                float D  = tm2[(7 + s) * TMP + 64 + i];
                float cu = cun[s], cs = csn[s], cl = cln[s];
                ncu += A * A * cu + 2.f * A * Bv * cs + Bv * Bv * cl;
                ncl += C * C * cu + 2.f * C * D * cs + D * D * cl;
                ncs += C * A * cu + (D * A + C * Bv) * cs + D * Bv * cl;
                au += A * muw[s] + Bv * mlw[s];
                al += C * muw[s] + D * mlw[s];
            }
            float denom = ncu + wcv;
            float inv = 1.f / denom;
            float qu = ncu * inv, ql = ncs * inv;
            float res = wmv - au;
            float pmu = au + qu * res;
            float pml = al + ql * res;
            float cf = 1.f - qu;
            cuR = cf * ncu;
            clR = ncl - ql * ncs;
            csR = cf * ncs;
            meanQ[i] = pmu;
            meanQ[64 + i] = pml;
            post_l[t * 128 + i] = pmu;
            post_l[t * 128 + 64 + i] = pml;
        }
        __syncthreads();   // BAR 5
    }

    // --- bulk-store post ---
    {
        const float4* s0 = (const float4*)post_l;
        float4* d0 = (float4*)(post_g + (long)b * (TT * 128));
        for (int idx = tid; idx < TT * 128 / 4; idx += 128)
            d0[idx] = s0[idx];
    }
}

// ---------------- decoder (unchanged) ----------------
#define DROWS 16
__global__ __launch_bounds__(256, 2)
void decoder_kernel(const float* __restrict__ post,
                    const float* __restrict__ dec_W, const float* __restrict__ dec_b,
                    const float* __restrict__ varh_W, const float* __restrict__ varh_b,
                    const float* __restrict__ var_W, const float* __restrict__ var_b,
                    float* __restrict__ out) {
    __shared__ float post_s[DROWS][LSD];
    __shared__ float vh_s[DROWS][CH];
    int tid = threadIdx.x;
    long row0 = (long)blockIdx.x * DROWS;
    for (int idx = tid; idx < DROWS * LSD; idx += 256) {
        int r = idx >> 7, c = idx & 127;
        post_s[r][c] = post[(row0 + r) * LSD + c];
    }
    __syncthreads();
    {
        int c = tid & 127, rh = tid >> 7;
        int r0 = rh * 8;
        float acc[8];
        #pragma unroll
        for (int r = 0; r < 8; ++r) acc[r] = 0.f;
        for (int j = 0; j < LSD; ++j) {
            float w = varh_W[j * CH + c];
            #pragma unroll
            for (int r = 0; r < 8; ++r) acc[r] += post_s[r0 + r][j] * w;
        }
        float bb = varh_b[c];
        #pragma unroll
        for (int r = 0; r < 8; ++r) vh_s[r0 + r][c] = fmaxf(acc[r] + bb, 0.f);
    }
    {
        int c = tid & 63, g = tid >> 6;
        int r0 = g * 4;
        float acc[4];
        #pragma unroll
        for (int r = 0; r < 4; ++r) acc[r] = 0.f;
        for (int j = 0; j < LSD; ++j) {
            float w = dec_W[j * OUTD + c];
            #pragma unroll
            for (int r = 0; r < 4; ++r) acc[r] += post_s[r0 + r][j] * w;
        }
        float bb = dec_b[c];
        #pragma unroll
        for (int r = 0; r < 4; ++r) out[(row0 + r0 + r) * 128 + c] = acc[r] + bb;
    }
    __syncthreads();
    {
        int c = tid & 63, g = tid >> 6;
        int r0 = g * 4;
        float acc[4];
        #pragma unroll
        for (int r = 0; r < 4; ++r) acc[r] = 0.f;
        for (int j = 0; j < CH; ++j) {
            float w = var_W[j * OUTD + c];
            #pragma unroll
            for (int r = 0; r < 4; ++r) acc[r] += vh_s[r0 + r][j] * w;
        }
        float bb = var_b[c];
        #pragma unroll
        for (int r = 0; r < 4; ++r) out[(row0 + r0 + r) * 128 + 64 + c] = elup1f(acc[r] + bb);
    }
}

extern "C" void kernel_launch(void* const* d_in, const int* in_sizes, int n_in,
                              void* d_out, int out_size, void* d_ws, size_t ws_size,
                              hipStream_t stream) {
    const float* obs     = (const float*)d_in[0];
    const float* enc_W   = (const float*)d_in[1];
    const float* enc_b   = (const float*)d_in[2];
    const float* wmean_W = (const float*)d_in[3];
    const float* wmean_b = (const float*)d_in[4];
    const float* wcov_W  = (const float*)d_in[5];
    const float* wcov_b  = (const float*)d_in[6];
    const float* cW1     = (const float*)d_in[7];
    const float* cb1     = (const float*)d_in[8];
    const float* cW2     = (const float*)d_in[9];
    const float* cb2     = (const float*)d_in[10];
    const float* tm11    = (const float*)d_in[11];
    const float* tm12    = (const float*)d_in[12];
    const float* tm21    = (const float*)d_in[13];
    const float* tm22    = (const float*)d_in[14];
    const float* log_tc  = (const float*)d_in[15];
    const float* dec_W   = (const float*)d_in[16];
    const float* dec_b   = (const float*)d_in[17];
    const float* varh_W  = (const float*)d_in[18];
    const float* varh_b  = (const float*)d_in[19];
    const float* var_W   = (const float*)d_in[20];
    const float* var_b   = (const float*)d_in[21];

    float* out = (float*)d_out;
    float* ws = (float*)d_ws;
    float* wm_ws    = ws;                 // 12288*64
    float* wc_ws    = ws + 786432;        // 12288*64
    float* post_ws  = ws + 1572864;       // 12288*128
    float* basis_ws = ws + 3145728;       // 16*128*14

    size_t dyn = (size_t)(TT * 128) * sizeof(float);  // 49152 B (post)
    (void)hipFuncSetAttribute((const void*)scan_kernel,
                              hipFuncAttributeMaxDynamicSharedMemorySize,
                              (int)dyn);

    clock_probe<<<128, 256, 0, stream>>>(basis_ws);   // diagnostic; overwritten below
    prep_basis<<<112, 256, 0, stream>>>(tm11, tm12, tm21, tm22, basis_ws);
    encoder_kernel<<<768, 256, 0, stream>>>(obs, enc_W, enc_b, wmean_W, wmean_b,
                                            wcov_W, wcov_b, wm_ws, wc_ws);
    scan_kernel<<<128, 128, dyn, stream>>>(wm_ws, wc_ws, cW1, cb1, cW2, cb2,
                                           basis_ws, log_tc, post_ws);
    decoder_kernel<<<768, 256, 0, stream>>>(post_ws, dec_W, dec_b, varh_W, varh_b,
                                            var_W, var_b, out);
}

// Round 8
// 290.872 us; speedup vs baseline: 3.0729x; 3.0729x over previous
//
#include <hip/hip_runtime.h>
#include <math.h>

#define LOD 64
#define LSD 128
#define KK 16
#define BB 128
#define TT 96
#define OBSD 128
#define ENC 512
#define CH 128
#define OUTD 64
#define TMP 132   // tm2 row pad

__device__ __forceinline__ float elup1f(float x) {
    return x >= 0.0f ? x + 1.0f : expf(x);
}

// ---------------- prep: band-compress basis (entry e = 14*row + s) ----------------
__global__ void prep_basis(const float* __restrict__ tm11, const float* __restrict__ tm12,
                           const float* __restrict__ tm21, const float* __restrict__ tm22,
                           float* __restrict__ basis) {
    int e = blockIdx.x * blockDim.x + threadIdx.x;
    if (e >= 16 * 128 * 14) return;
    int k = e / (128 * 14);
    int rem = e % (128 * 14);
    int row = rem / 14;
    int s = rem % 14;
    int r = row & 63;
    int half = row >> 6;
    int sub = (s >= 7) ? 1 : 0;
    int ss = s - sub * 7;
    int col = r - 3 + ss;
    float v = 0.0f;
    if (col >= 0 && col < 64) {
        const float* src = half ? (sub ? tm22 : tm21) : (sub ? tm12 : tm11);
        v = src[k * 4096 + r * 64 + col];
    }
    basis[e] = v;
}

// ---------------- encoder (unchanged) ----------------
#define EROWS 16
__global__ __launch_bounds__(256, 2)
void encoder_kernel(const float* __restrict__ obs,
                    const float* __restrict__ enc_W, const float* __restrict__ enc_b,
                    const float* __restrict__ wmean_W, const float* __restrict__ wmean_b,
                    const float* __restrict__ wcov_W, const float* __restrict__ wcov_b,
                    float* __restrict__ wm_out, float* __restrict__ wc_out) {
    __shared__ float obs_s[EROWS][OBSD];
    __shared__ float h_s[EROWS][ENC];
    __shared__ float wm_s[EROWS][LOD];
    __shared__ float norm_s[EROWS];
    int tid = threadIdx.x;
    long row0 = (long)blockIdx.x * EROWS;

    for (int idx = tid; idx < EROWS * OBSD; idx += 256) {
        int r = idx >> 7, c = idx & 127;
        obs_s[r][c] = obs[(row0 + r) * OBSD + c];
    }
    __syncthreads();

    for (int p = 0; p < 2; ++p) {
        int c = tid + p * 256;
        float acc[EROWS];
        #pragma unroll
        for (int r = 0; r < EROWS; ++r) acc[r] = 0.f;
        for (int j = 0; j < OBSD; ++j) {
            float w = enc_W[j * ENC + c];
            #pragma unroll
            for (int r = 0; r < EROWS; ++r) acc[r] += obs_s[r][j] * w;
        }
        float b = enc_b[c];
        #pragma unroll
        for (int r = 0; r < EROWS; ++r) h_s[r][c] = fmaxf(acc[r] + b, 0.f);
    }
    __syncthreads();

    {
        int c = tid & 63, g = tid >> 6;
        const float* W = (g < 2) ? wmean_W : wcov_W;
        int r0 = (g & 1) * 8;
        float acc[8];
        #pragma unroll
        for (int r = 0; r < 8; ++r) acc[r] = 0.f;
        for (int j = 0; j < ENC; ++j) {
            float w = W[j * LOD + c];
            #pragma unroll
            for (int r = 0; r < 8; ++r) acc[r] += h_s[r0 + r][j] * w;
        }
        if (g < 2) {
            float b = wmean_b[c];
            #pragma unroll
            for (int r = 0; r < 8; ++r) wm_s[r0 + r][c] = acc[r] + b;
        } else {
            float b = wcov_b[c];
            #pragma unroll
            for (int r = 0; r < 8; ++r)
                wc_out[(row0 + r0 + r) * LOD + c] = elup1f(acc[r] + b);
        }
    }
    __syncthreads();
    if (tid < EROWS) {
        float ss = 0.f;
        for (int c = 0; c < 64; ++c) { float v = wm_s[tid][c]; ss += v * v; }
        norm_s[tid] = sqrtf(ss);
    }
    __syncthreads();
    for (int idx = tid; idx < EROWS * LOD; idx += 256) {
        int r = idx >> 6, c = idx & 63;
        wm_out[(row0 + r) * LOD + c] = wm_s[r][c] / norm_s[r];
    }
}

// ---------------- scan: 4 waves, 2 barriers/step, minimal dependency hops ----------------
// A (in-wave):  hh for wave's 32 cols; mean from WAVE-PRIVATE LDS slice (no barrier);
//               j-split over lane halves, one shfl_xor(32) combine.
// B (in-wave):  logit partials via 8 shfl + xor16/xor32; lanes<16 write part_s[w][k].
// BAR 1
// C (in-lane, ALL threads): 16 broadcast reads of part_s -> 16 exps in registers ->
//               normalized ck[16] per thread. NO ck exchange.
// D (registers): thread's 7 banded Tm entries = ck . br -> tm2 (conflict-free writes).
// BAR 2
// E (REDUNDANT in all 4 waves): banded cov/mean propagation + Kalman; carries in
//               registers (shfl taps); writes mean to wave-private slice; wave 0
//               also writes post_l. No barrier before next A.
__global__ __launch_bounds__(256, 1)
void scan_kernel(const float* __restrict__ wm_g, const float* __restrict__ wc_g,
                 const float* __restrict__ cW1, const float* __restrict__ cb1,
                 const float* __restrict__ cW2, const float* __restrict__ cb2,
                 const float* __restrict__ basis, const float* __restrict__ log_tc,
                 float* __restrict__ post_g) {
    extern __shared__ __align__(16) float smem[];
    float* wm_l   = smem;            // 6144
    float* wc_l   = smem + 6144;     // 6144
    float* post_l = smem + 12288;    // 12288

    __shared__ __align__(16) float meanW[4][136];   // per wave: [4 pad | mu 64 | ml 64 | 4 pad]
    __shared__ __align__(16) float part_s[4][16];
    __shared__ float tm2[16 * TMP];                 // [slot s][row r]

    int tid = threadIdx.x;
    int b = blockIdx.x;
    int w = tid >> 6;        // wave
    int l = tid & 63;        // lane
    int k = l & 15;
    int p = l >> 4;          // 0..3: 8-col group within wave's 32 cols

    // --- bulk-load this batch's wm/wc into LDS ---
    {
        const float4* s0 = (const float4*)(wm_g + (long)b * (TT * 64));
        const float4* s1 = (const float4*)(wc_g + (long)b * (TT * 64));
        float4* d0 = (float4*)wm_l;
        float4* d1 = (float4*)wc_l;
        for (int idx = tid; idx < TT * 64 / 4; idx += 256) {
            d0[idx] = s0[idx];
            d1[idx] = s1[idx];
        }
    }

    // --- persistent registers ---
    float br[16][7];         // basis entries e = 7*tid + j, all 16 k
    #pragma unroll
    for (int q = 0; q < 16; ++q)
        #pragma unroll
        for (int j = 0; j < 7; ++j)
            br[q][j] = basis[q * 1792 + 7 * tid + j];

    int c = 32 * w + (l & 31);          // hh column (2 lanes redundant per col)
    int jhalf = (l >= 32) ? 64 : 0;     // j-half this lane covers
    float w1r[64];
    #pragma unroll
    for (int jj = 0; jj < 64; ++jj)
        w1r[jj] = cW1[(jhalf + jj) * 128 + c];
    float cb1r = cb1[c];

    float w2r[8];                       // cW2[(32w+8p+u)][k]
    #pragma unroll
    for (int u = 0; u < 8; ++u)
        w2r[u] = cW2[(32 * w + 8 * p + u) * 16 + k];
    float cb2r = cb2[k];

    // FG state, redundant per wave: lane l owns row l
    float cuR = 10.f, clR = 10.f, csR = 0.f;
    float tcu_r = elup1f(log_tc[l]);
    float tcl_r = elup1f(log_tc[64 + l]);

    // --- init wave-private mean slices (+pads) ---
    for (int idx = l; idx < 136; idx += 64) meanW[w][idx] = 0.f;
    __syncthreads();

    #pragma clang loop unroll(disable)
    for (int t = 0; t < TT; ++t) {
        // prefetch (wave-private; latency hidden under A..D)
        float wmv = wm_l[t * 64 + l];
        float wcv = wc_l[t * 64 + l];
        float muw[7], mlw[7];
        #pragma unroll
        for (int d = 0; d < 7; ++d) {
            muw[d] = meanW[w][4 + l + d - 3];    // pads make edges safe (band entry = 0)
            mlw[d] = meanW[w][68 + l + d - 3];
        }

        // ---- A: hh for wave's 32 cols (j-split halves, 1 shfl combine) ----
        float hh;
        {
            const float4* mq = (const float4*)(&meanW[w][4 + jhalf]);
            float a0 = 0.f, a1 = 0.f, a2 = 0.f, a3 = 0.f;
            #pragma unroll
            for (int j4 = 0; j4 < 16; ++j4) {
                float4 m4 = mq[j4];
                a0 += m4.x * w1r[4 * j4 + 0];
                a1 += m4.y * w1r[4 * j4 + 1];
                a2 += m4.z * w1r[4 * j4 + 2];
                a3 += m4.w * w1r[4 * j4 + 3];
            }
            float acc = (a0 + a1) + (a2 + a3);
            acc += __shfl_xor(acc, 32, 64);
            hh = fmaxf(acc + cb1r, 0.f);
        }

        // ---- B: logit partials (8 shfl + 2 xor), lanes<16 publish ----
        {
            float pl = 0.f;
            #pragma unroll
            for (int u = 0; u < 8; ++u)
                pl += __shfl(hh, 8 * p + u, 64) * w2r[u];
            pl += __shfl_xor(pl, 16, 64);
            pl += __shfl_xor(pl, 32, 64);
            if (l < 16) part_s[w][l] = pl + ((w == 0) ? cb2r : 0.f);
        }
        __syncthreads();   // BAR 1

        // ---- C: in-lane softmax over 16 logits (every thread, broadcast reads) ----
        float ck[16];
        {
            const float4* pq = (const float4*)(&part_s[0][0]);   // quad g of wave w' = pq[4w'+g]
            float sm = 0.f;
            #pragma unroll
            for (int g = 0; g < 4; ++g) {
                float4 a = pq[g], b2 = pq[4 + g], c2 = pq[8 + g], d2 = pq[12 + g];
                float e0 = __expf(a.x + b2.x + c2.x + d2.x);
                float e1 = __expf(a.y + b2.y + c2.y + d2.y);
                float e2 = __expf(a.z + b2.z + c2.z + d2.z);
                float e3 = __expf(a.w + b2.w + c2.w + d2.w);
                ck[4 * g + 0] = e0; ck[4 * g + 1] = e1;
                ck[4 * g + 2] = e2; ck[4 * g + 3] = e3;
                sm += (e0 + e1) + (e2 + e3);
            }
            float inv = 1.f / sm;
            #pragma unroll
            for (int q = 0; q < 16; ++q) ck[q] *= inv;
        }

        // ---- D: banded Tm entries (pure-register dot, 7 writes) ----
        {
            int r = tid >> 1;
            int s0 = (tid & 1) * 7;
            #pragma unroll
            for (int j = 0; j < 7; ++j) {
                float acc = 0.f;
                #pragma unroll
                for (int q = 0; q < 16; ++q) acc += ck[q] * br[q][j];
                tm2[(s0 + j) * TMP + r] = acc;
            }
        }
        __syncthreads();   // BAR 2

        // ---- E: banded propagation + Kalman, REDUNDANT in all 4 waves ----
        {
            int i = l;
            float cun[7], csn[7], cln[7];
            #pragma unroll
            for (int d = 0; d < 7; ++d) {
                int src = i + d - 3;
                cun[d] = __shfl(cuR, src, 64);   // out-of-range taps pair with 0 band entries
                csn[d] = __shfl(csR, src, 64);
                cln[d] = __shfl(clR, src, 64);
            }
            float ncu = tcu_r, ncl = tcl_r, ncs = 0.f, au = 0.f, al = 0.f;
            #pragma unroll
            for (int s = 0; s < 7; ++s) {
                float A  = tm2[s * TMP + i];
                float Bv = tm2[(7 + s) * TMP + i];
                float C  = tm2[s * TMP + 64 + i];
                float D  = tm2[(7 + s) * TMP + 64 + i];
                float cu = cun[s], cs = csn[s], cl = cln[s];
                ncu += A * A * cu + 2.f * A * Bv * cs + Bv * Bv * cl;
                ncl += C * C * cu + 2.f * C * D * cs + D * D * cl;
                ncs += C * A * cu + (D * A + C * Bv) * cs + D * Bv * cl;
                au += A * muw[s] + Bv * mlw[s];
                al += C * muw[s] + D * mlw[s];
            }
            float denom = ncu + wcv;
            float inv = 1.f / denom;
            float qu = ncu * inv, ql = ncs * inv;
            float res = wmv - au;
            float pmu = au + qu * res;
            float pml = al + ql * res;
            float cf = 1.f - qu;
            cuR = cf * ncu;
            clR = ncl - ql * ncs;
            csR = cf * ncs;
            meanW[w][4 + i] = pmu;      // wave-private: next A reads it, no barrier
            meanW[w][68 + i] = pml;
            if (w == 0) {
                post_l[t * 128 + i] = pmu;
                post_l[t * 128 + 64 + i] = pml;
            }
        }
        // no barrier: tm2/part_s reuse is fenced by the BAR1/BAR2 alternation
    }

    __syncthreads();
    // --- bulk-store post ---
    {
        const float4* s0 = (const float4*)post_l;
        float4* d0 = (float4*)(post_g + (long)b * (TT * 128));
        for (int idx = tid; idx < TT * 128 / 4; idx += 256)
            d0[idx] = s0[idx];
    }
}

// ---------------- decoder (unchanged) ----------------
#define DROWS 16
__global__ __launch_bounds__(256, 2)
void decoder_kernel(const float* __restrict__ post,
                    const float* __restrict__ dec_W, const float* __restrict__ dec_b,
                    const float* __restrict__ varh_W, const float* __restrict__ varh_b,
                    const float* __restrict__ var_W, const float* __restrict__ var_b,
                    float* __restrict__ out) {
    __shared__ float post_s[DROWS][LSD];
    __shared__ float vh_s[DROWS][CH];
    int tid = threadIdx.x;
    long row0 = (long)blockIdx.x * DROWS;
    for (int idx = tid; idx < DROWS * LSD; idx += 256) {
        int r = idx >> 7, c = idx & 127;
        post_s[r][c] = post[(row0 + r) * LSD + c];
    }
    __syncthreads();
    {
        int c = tid & 127, rh = tid >> 7;
        int r0 = rh * 8;
        float acc[8];
        #pragma unroll
        for (int r = 0; r < 8; ++r) acc[r] = 0.f;
        for (int j = 0; j < LSD; ++j) {
            float w = varh_W[j * CH + c];
            #pragma unroll
            for (int r = 0; r < 8; ++r) acc[r] += post_s[r0 + r][j] * w;
        }
        float bb = varh_b[c];
        #pragma unroll
        for (int r = 0; r < 8; ++r) vh_s[r0 + r][c] = fmaxf(acc[r] + bb, 0.f);
    }
    {
        int c = tid & 63, g = tid >> 6;
        int r0 = g * 4;
        float acc[4];
        #pragma unroll
        for (int r = 0; r < 4; ++r) acc[r] = 0.f;
        for (int j = 0; j < LSD; ++j) {
            float w = dec_W[j * OUTD + c];
            #pragma unroll
            for (int r = 0; r < 4; ++r) acc[r] += post_s[r0 + r][j] * w;
        }
        float bb = dec_b[c];
        #pragma unroll
        for (int r = 0; r < 4; ++r) out[(row0 + r0 + r) * 128 + c] = acc[r] + bb;
    }
    __syncthreads();
    {
        int c = tid & 63, g = tid >> 6;
        int r0 = g * 4;
        float acc[4];
        #pragma unroll
        for (int r = 0; r < 4; ++r) acc[r] = 0.f;
        for (int j = 0; j < CH; ++j) {
            float w = var_W[j * OUTD + c];
            #pragma unroll
            for (int r = 0; r < 4; ++r) acc[r] += vh_s[r0 + r][j] * w;
        }
        float bb = var_b[c];
        #pragma unroll
        for (int r = 0; r < 4; ++r) out[(row0 + r0 + r) * 128 + 64 + c] = elup1f(acc[r] + bb);
    }
}

extern "C" void kernel_launch(void* const* d_in, const int* in_sizes, int n_in,
                              void* d_out, int out_size, void* d_ws, size_t ws_size,
                              hipStream_t stream) {
    const float* obs     = (const float*)d_in[0];
    const float* enc_W   = (const float*)d_in[1];
    const float* enc_b   = (const float*)d_in[2];
    const float* wmean_W = (const float*)d_in[3];
    const float* wmean_b = (const float*)d_in[4];
    const float* wcov_W  = (const float*)d_in[5];
    const float* wcov_b  = (const float*)d_in[6];
    const float* cW1     = (const float*)d_in[7];
    const float* cb1     = (const float*)d_in[8];
    const float* cW2     = (const float*)d_in[9];
    const float* cb2     = (const float*)d_in[10];
    const float* tm11    = (const float*)d_in[11];
    const float* tm12    = (const float*)d_in[12];
    const float* tm21    = (const float*)d_in[13];
    const float* tm22    = (const float*)d_in[14];
    const float* log_tc  = (const float*)d_in[15];
    const float* dec_W   = (const float*)d_in[16];
    const float* dec_b   = (const float*)d_in[17];
    const float* varh_W  = (const float*)d_in[18];
    const float* varh_b  = (const float*)d_in[19];
    const float* var_W   = (const float*)d_in[20];
    const float* var_b   = (const float*)d_in[21];

    float* out = (float*)d_out;
    float* ws = (float*)d_ws;
    float* wm_ws    = ws;                 // 12288*64
    float* wc_ws    = ws + 786432;        // 12288*64
    float* post_ws  = ws + 1572864;       // 12288*128
    float* basis_ws = ws + 3145728;       // 16*128*14

    size_t dyn = (size_t)(6144 + 6144 + 12288) * sizeof(float);  // 98304 B
    (void)hipFuncSetAttribute((const void*)scan_kernel,
                              hipFuncAttributeMaxDynamicSharedMemorySize,
                              (int)dyn);

    prep_basis<<<112, 256, 0, stream>>>(tm11, tm12, tm21, tm22, basis_ws);
    encoder_kernel<<<768, 256, 0, stream>>>(obs, enc_W, enc_b, wmean_W, wmean_b,
                                            wcov_W, wcov_b, wm_ws, wc_ws);
    scan_kernel<<<128, 256, dyn, stream>>>(wm_ws, wc_ws, cW1, cb1, cW2, cb2,
                                           basis_ws, log_tc, post_ws);
    decoder_kernel<<<768, 256, 0, stream>>>(post_ws, dec_W, dec_b, varh_W, varh_b,
                                            var_W, var_b, out);
}